// Round 5
// baseline (140.730 us; speedup 1.0000x reference)
//
#include <hip/hip_runtime.h>
#include <hip/hip_bf16.h>
#include <math.h>

// Problem constants (fixed by setup_inputs)
#define NB      2      // batch
#define T_IN    12
#define T_OUT_  24
#define O_OUT   12     // T_OUT - T_IN
#define NN      10000  // nodes
#define CC      16     // channels
#define KK      17     // neighbors
#define HH      4      // heads
#define JJ      48     // T_IN * HH
#define NPC     80     // nodes per chunk
#define NCHUNK  125    // 125 * 80 = 10000
#define PPG     3      // planes per group (24 planes / 8 XCD groups)
#define NPS     4      // nodes per shrink block

// ---- bf16 helpers (RNE pack, shift unpack) ----
__device__ __forceinline__ unsigned int f2bf(float f) {
    union { float f; unsigned int u; } v; v.f = f;
    unsigned int r = v.u + 0x7FFFu + ((v.u >> 16) & 1u);
    return r >> 16;
}
__device__ __forceinline__ float bf2f(unsigned int lo16) {
    union { unsigned int u; float f; } v; v.u = lo16 << 16;
    return v.f;
}

// ---------------- sigma = max(nearest_dists), multi-block -------------------
// dists >= 0 so int-bit compare == float compare. Initial ws state is either
// 0xAAAAAAAA (harness poison -> negative int) or 0 -- both below any valid
// max (max dist ~1.0 > 0), so no zero-init dispatch is needed.
__global__ __launch_bounds__(256) void sigma_reduce_kernel(
    const float* __restrict__ d, int n, int* __restrict__ out) {
    float m = 0.0f;
    const int nv4 = n >> 2;
    const float4* d4 = (const float4*)d;
    for (int i = blockIdx.x * 256 + threadIdx.x; i < nv4; i += gridDim.x * 256) {
        float4 v = d4[i];
        m = fmaxf(fmaxf(m, fmaxf(v.x, v.y)), fmaxf(v.z, v.w));
    }
    for (int i = (nv4 << 2) + blockIdx.x * 256 + threadIdx.x; i < n;
         i += gridDim.x * 256)
        m = fmaxf(m, d[i]);
    #pragma unroll
    for (int off = 32; off > 0; off >>= 1)
        m = fmaxf(m, __shfl_down(m, off, 64));
    __shared__ float sm[4];
    int lane = threadIdx.x & 63, wid = threadIdx.x >> 6;
    if (lane == 0) sm[wid] = m;
    __syncthreads();
    if (threadIdx.x == 0) {
        float mm = fmaxf(fmaxf(sm[0], sm[1]), fmaxf(sm[2], sm[3]));
        atomicMax(out, __float_as_int(mm));   // signed: works over 0xAA poison
    }
}

// ---------------- phase 1: fused weights + gather + aggregate ---------------
// grid = 8 groups x 125 chunks. group g owns planes {g, g+8, g+16} (same XCD
// under the blockIdx%8 heuristic) -> 3 planes (1.9 MB) stay L2-resident.
// 320 threads = 80 node-lanes x 4 channel-quads; gather is float4 per lane
// (4 lanes cover one 64B neighbor row). Weights computed at staging (f32).
// agg layout: (n, b, t, c, h) bf16 -> two dwordx4 stores per (thread, plane).
__global__ __launch_bounds__(320) void aggregate_kernel(
    const float* __restrict__ x,
    const int*   __restrict__ nodes,
    const float* __restrict__ dists,
    const int*   __restrict__ sigma_bits,
    float* __restrict__ out,
    unsigned short* __restrict__ agg)
{
    const int g     = blockIdx.x & 7;
    const int chunk = blockIdx.x >> 3;       // 0..124
    const int n0    = chunk * NPC;
    const int tid   = threadIdx.x;

    __shared__ int   lds_idx[NPC * KK];      // 5.4 KB  (byte offsets)
    __shared__ float lds_w[NPC * KK][HH];    // 21.8 KB (f32 weights)

    // ---- stage records: compute weights on the fly ----
    const float sigma  = __int_as_float(*sigma_bits);
    const float inv_s2 = 1.0f / (sigma * sigma);
    const int rbase = n0 * KK;
    for (int j = tid; j < NPC * KK; j += 320) {
        const int   nd = nodes[rbase + j];
        const float dd = dists[rbase + j];
        const float q  = dd * dd * inv_s2;
        const float e1 = expf(-q * 0.25f);   // w_h = e1^(h+1)
        float w0 = e1, w1 = e1 * e1, w2 = w1 * e1, w3 = w1 * w1;
        if (nd == -1) { w0 = w1 = w2 = w3 = 0.f; }
        if (w0 < 1e-8f) w0 = 0.f;
        if (w1 < 1e-8f) w1 = 0.f;
        if (w2 < 1e-8f) w2 = 0.f;
        if (w3 < 1e-8f) w3 = 0.f;
        lds_idx[j]  = ((nd < 0) ? 0 : nd) * (CC * 4);
        lds_w[j][0] = w0; lds_w[j][1] = w1; lds_w[j][2] = w2; lds_w[j][3] = w3;
    }
    __syncthreads();

    // plane set for this group
    int plane[PPG], bb[PPG], tt[PPG];
    const char* xb[PPG];
    #pragma unroll
    for (int p = 0; p < PPG; ++p) {
        plane[p] = g + 8 * p;                // 0..23
        bb[p] = plane[p] / T_IN;
        tt[p] = plane[p] % T_IN;
        xb[p] = (const char*)(x + (long)plane[p] * NN * CC);
    }

    const int q  = tid & 3;                  // channel quad (c = 4q..4q+3)
    const int nl = tid >> 2;                 // 0..79 node within chunk
    const int n  = n0 + nl;
    const int rb = nl * KK;
    const int qb = q * 16;                   // byte offset within 64B row

    float4 acc[PPG][HH];
    #pragma unroll
    for (int p = 0; p < PPG; ++p)
        #pragma unroll
        for (int h = 0; h < HH; ++h)
            acc[p][h] = make_float4(0.f, 0.f, 0.f, 0.f);

    #pragma unroll
    for (int k = 0; k < KK; ++k) {
        const int   off = lds_idx[rb + k] + qb;
        const float w0 = lds_w[rb + k][0];
        const float w1 = lds_w[rb + k][1];
        const float w2 = lds_w[rb + k][2];
        const float w3 = lds_w[rb + k][3];
        float4 gv[PPG];
        #pragma unroll
        for (int p = 0; p < PPG; ++p)
            gv[p] = *(const float4*)(xb[p] + off);
        #pragma unroll
        for (int p = 0; p < PPG; ++p) {
            acc[p][0].x += gv[p].x * w0; acc[p][0].y += gv[p].y * w0;
            acc[p][0].z += gv[p].z * w0; acc[p][0].w += gv[p].w * w0;
            acc[p][1].x += gv[p].x * w1; acc[p][1].y += gv[p].y * w1;
            acc[p][1].z += gv[p].z * w1; acc[p][1].w += gv[p].w * w1;
            acc[p][2].x += gv[p].x * w2; acc[p][2].y += gv[p].y * w2;
            acc[p][2].z += gv[p].z * w2; acc[p][2].w += gv[p].w * w2;
            acc[p][3].x += gv[p].x * w3; acc[p][3].y += gv[p].y * w3;
            acc[p][3].z += gv[p].z * w3; acc[p][3].w += gv[p].w * w3;
        }
    }

    #pragma unroll
    for (int p = 0; p < PPG; ++p) {
        // agg (n,b,t,c,h): uint2 index = ((n*NB+b)*T_IN+t)*CC + c, c = 4q+j
        const long base = ((long)(n * NB + bb[p]) * T_IN + tt[p]) * CC + q * 4;
        uint4 s0, s1;
        s0.x = f2bf(acc[p][0].x) | (f2bf(acc[p][1].x) << 16);
        s0.y = f2bf(acc[p][2].x) | (f2bf(acc[p][3].x) << 16);
        s0.z = f2bf(acc[p][0].y) | (f2bf(acc[p][1].y) << 16);
        s0.w = f2bf(acc[p][2].y) | (f2bf(acc[p][3].y) << 16);
        s1.x = f2bf(acc[p][0].z) | (f2bf(acc[p][1].z) << 16);
        s1.y = f2bf(acc[p][2].z) | (f2bf(acc[p][3].z) << 16);
        s1.z = f2bf(acc[p][0].w) | (f2bf(acc[p][1].w) << 16);
        s1.w = f2bf(acc[p][2].w) | (f2bf(acc[p][3].w) << 16);
        uint4* dst = (uint4*)((uint2*)agg + base);
        dst[0] = s0;
        dst[1] = s1;
    }

    // ---- passthrough for the 3 planes: out[b,t,chunk] = x[b,t,chunk] ----
    #pragma unroll
    for (int p = 0; p < PPG; ++p) {
        const float4* src = (const float4*)(x + (long)plane[p] * NN * CC + n0 * CC);
        float4* dst = (float4*)(out + (long)(bb[p] * T_OUT_ + tt[p]) * NN * CC + n0 * CC);
        dst[tid] = src[tid];                 // exactly 320 float4 per plane
    }
}

// ---------------- phase 2: 48-term shrink matmul + SELU ----------------
// 4 nodes per block; agg read directly from global (o-lanes dedup to the
// same 128B line within a wave); only W/bias staged in LDS.
__global__ __launch_bounds__(384) void shrink_kernel(
    const unsigned short* __restrict__ agg,
    const float* __restrict__ Wm, const float* __restrict__ bias,
    float* __restrict__ out)
{
    const int tid = threadIdx.x;

    __shared__ float W_s[O_OUT * JJ];   // 2.25 KB
    __shared__ float b_s[O_OUT];

    for (int i = tid; i < O_OUT * JJ; i += 384) W_s[i] = Wm[i];
    if (tid < O_OUT) b_s[tid] = bias[tid];
    __syncthreads();

    const int c    = tid & 15;
    const int rest = tid >> 4;      // 0..23
    const int o    = rest % O_OUT;
    const int b    = rest / O_OUT;

    const float kScale = 1.0507009873554805f;
    const float kAlpha = 1.6732632423543772f;

    #pragma unroll
    for (int u = 0; u < NPS; ++u) {
        const int n = blockIdx.x * NPS + u;
        // agg (n,b,t,c,h): uint2 index = ((n*NB+b)*T_IN+t)*CC + c
        const uint2* ap = (const uint2*)agg + ((long)(n * NB + b) * T_IN) * CC + c;

        float y = b_s[o];
        #pragma unroll
        for (int t = 0; t < T_IN; ++t) {
            const uint2 v = ap[t * CC];
            const int wb = o * JJ + t * HH;
            y += bf2f(v.x & 0xffffu) * W_s[wb + 0];
            y += bf2f(v.x >> 16)     * W_s[wb + 1];
            y += bf2f(v.y & 0xffffu) * W_s[wb + 2];
            y += bf2f(v.y >> 16)     * W_s[wb + 3];
        }

        y = (y > 0.0f) ? kScale * y : kScale * kAlpha * expm1f(y);
        out[((long)(b * T_OUT_ + T_IN + o) * NN + n) * CC + c] = y;
    }
}

extern "C" void kernel_launch(void* const* d_in, const int* in_sizes, int n_in,
                              void* d_out, int out_size, void* d_ws, size_t ws_size,
                              hipStream_t stream) {
    const float* x     = (const float*)d_in[0];
    const int*   nodes = (const int*)  d_in[1];
    const float* dists = (const float*)d_in[2];
    const float* Wm    = (const float*)d_in[3];
    const float* bias  = (const float*)d_in[4];
    float* out = (float*)d_out;

    // ws layout: [0,4)=sigma (int bits) | 256: agg (N*B*T*C*H bf16, 30.72 MB)
    char* ws = (char*)d_ws;
    int*            sigma_bits = (int*)ws;
    unsigned short* agg        = (unsigned short*)(ws + 256);

    const int nd = in_sizes[2];  // N*K = 170000
    sigma_reduce_kernel<<<167, 256, 0, stream>>>(dists, nd, sigma_bits);
    aggregate_kernel<<<8 * NCHUNK, 320, 0, stream>>>(x, nodes, dists,
                                                     sigma_bits, out, agg);
    shrink_kernel<<<NN / NPS, 384, 0, stream>>>(agg, Wm, bias, out);
}

// Round 6
// 117.787 us; speedup vs baseline: 1.1948x; 1.1948x over previous
//
#include <hip/hip_runtime.h>
#include <hip/hip_bf16.h>
#include <math.h>

// Problem constants (fixed by setup_inputs)
#define NB      2      // batch
#define T_IN    12
#define T_OUT_  24
#define O_OUT   12     // T_OUT - T_IN
#define NN      10000  // nodes
#define CC      16     // channels
#define KK      17     // neighbors
#define HH      4      // heads
#define JJ      48     // T_IN * HH
#define PL      24     // planes = NB * T_IN
#define TN      64     // transpose: nodes per block
#define TBLK    157    // ceil(NN / TN)
#define SBLK    167    // sigma blocks (167*256*4 >= 170000)
#define GN      8      // fused: nodes per block
#define GBLK    1250   // NN / GN
#define PSTR    68     // a_s plane stride (floats): 16B-aligned, bank-rotating
#define ANS     (PL * PSTR)   // a_s node stride = 1632 floats

// ---- bf16 helpers (RNE pack, shift unpack) ----
__device__ __forceinline__ unsigned int f2bf(float f) {
    union { float f; unsigned int u; } v; v.f = f;
    unsigned int r = v.u + 0x7FFFu + ((v.u >> 16) & 1u);
    return r >> 16;
}
__device__ __forceinline__ float bf2f(unsigned int lo16) {
    union { unsigned int u; float f; } v; v.u = lo16 << 16;
    return v.f;
}

// ---------------- dispatch 1: transpose x -> xt(bf16) + passthrough + sigma --
// blocks [0,TBLK): transpose 64 nodes x 24 planes; also writes out[b][t] copy.
// blocks [TBLK, TBLK+SBLK): sigma = max(dists) via signed atomicMax (dists>=0,
// ws poison 0xAA...AA is a negative int -> below any valid max, no memset).
__global__ __launch_bounds__(256) void setup_kernel(
    const float* __restrict__ x,
    const float* __restrict__ dists, int ndists,
    float* __restrict__ out,
    unsigned short* __restrict__ xt,
    int* __restrict__ sigma_bits)
{
    const int tid = threadIdx.x;
    if (blockIdx.x < TBLK) {
        // ---- transpose part ----
        const int n0 = blockIdx.x * TN;
        const int q  = tid & 3;        // channel quad (c = 4q..4q+3)
        const int nl = tid >> 2;       // 0..63
        const int n  = n0 + nl;
        if (n < NN) {
            uint2* xtp = (uint2*)xt + n * (PL * 4) + q;  // node row, quad q
            #pragma unroll
            for (int p = 0; p < PL; ++p) {
                const float4 v = *(const float4*)(x + (p * NN + n) * CC + q * 4);
                // passthrough: out[b, t, n, c] = x   (plane p = b*T_IN + t)
                const int b = p / T_IN, t = p % T_IN;
                *(float4*)(out + ((b * T_OUT_ + t) * NN + n) * CC + q * 4) = v;
                uint2 pk;
                pk.x = f2bf(v.x) | (f2bf(v.y) << 16);
                pk.y = f2bf(v.z) | (f2bf(v.w) << 16);
                xtp[p * 4] = pk;
            }
        }
    } else {
        // ---- sigma part ----
        const int sb = blockIdx.x - TBLK;
        float m = 0.0f;
        const int nv4 = ndists >> 2;
        const float4* d4 = (const float4*)dists;
        for (int i = sb * 256 + tid; i < nv4; i += SBLK * 256) {
            float4 v = d4[i];
            m = fmaxf(fmaxf(m, fmaxf(v.x, v.y)), fmaxf(v.z, v.w));
        }
        for (int i = (nv4 << 2) + sb * 256 + tid; i < ndists; i += SBLK * 256)
            m = fmaxf(m, dists[i]);
        #pragma unroll
        for (int off = 32; off > 0; off >>= 1)
            m = fmaxf(m, __shfl_down(m, off, 64));
        __shared__ float sm[4];
        int lane = tid & 63, wid = tid >> 6;
        if (lane == 0) sm[wid] = m;
        __syncthreads();
        if (tid == 0) {
            float mm = fmaxf(fmaxf(sm[0], sm[1]), fmaxf(sm[2], sm[3]));
            atomicMax(sigma_bits, __float_as_int(mm));
        }
    }
}

// ---------------- dispatch 2: fused gather + aggregate + shrink + SELU ------
// Block = 384 threads = 4 node-slots x 96 lanes; lane96 = plane*4 + q covers a
// node's full 768B xt row (coalesced). 8 nodes/block in 2 rounds of 4.
// agg stays f32 in registers -> LDS (a_s) -> 48-term shrink dot, no global agg.
__global__ __launch_bounds__(384) void fused_kernel(
    const unsigned short* __restrict__ xt,
    const int*   __restrict__ nodes,
    const float* __restrict__ dists,
    const int*   __restrict__ sigma_bits,
    const float* __restrict__ Wm,
    const float* __restrict__ bias,
    float* __restrict__ out)
{
    const int tid = threadIdx.x;
    const int n0  = blockIdx.x * GN;

    __shared__ int   lidx[GN * KK];        // xt byte offsets
    __shared__ float lw[GN * KK][HH];      // f32 weights
    __shared__ float W_s[O_OUT * JJ];      // 2.25 KB
    __shared__ float b_s[O_OUT];
    __shared__ float a_s[4 * ANS];         // 4 nodes x (24 planes x 16c x 4h), padded

    // ---- stage W, bias, records ----
    for (int i = tid; i < O_OUT * JJ; i += 384) W_s[i] = Wm[i];
    if (tid < O_OUT) b_s[tid] = bias[tid];

    const float sigma  = __int_as_float(*sigma_bits);
    const float inv_s2 = 1.0f / (sigma * sigma);
    if (tid < GN * KK) {
        const int   nd = nodes[n0 * KK + tid];
        const float dd = dists[n0 * KK + tid];
        const float e1 = expf(-dd * dd * inv_s2 * 0.25f);  // w_h = e1^(h+1)
        float w0 = e1, w1 = e1 * e1, w2 = w1 * e1, w3 = w1 * w1;
        if (nd == -1) { w0 = w1 = w2 = w3 = 0.f; }
        if (w0 < 1e-8f) w0 = 0.f;
        if (w1 < 1e-8f) w1 = 0.f;
        if (w2 < 1e-8f) w2 = 0.f;
        if (w3 < 1e-8f) w3 = 0.f;
        lidx[tid]  = ((nd < 0) ? 0 : nd) * (PL * CC * 2);  // 768 B per node row
        lw[tid][0] = w0; lw[tid][1] = w1; lw[tid][2] = w2; lw[tid][3] = w3;
    }
    __syncthreads();

    const int slot = tid / 96;             // node slot 0..3
    const int l96  = tid % 96;             // plane*4 + q

    const float kScale = 1.0507009873554805f;
    const float kAlpha = 1.6732632423543772f;

    for (int g = 0; g < GN / 4; ++g) {
        const int nl = g * 4 + slot;       // node local 0..GN-1
        const int rb = nl * KK;

        float4 ah0 = {0,0,0,0}, ah1 = {0,0,0,0}, ah2 = {0,0,0,0}, ah3 = {0,0,0,0};
        #pragma unroll
        for (int k = 0; k < KK; ++k) {
            const uint2 gv = *(const uint2*)((const char*)xt + lidx[rb + k] + l96 * 8);
            const float g0 = bf2f(gv.x & 0xffffu), g1 = bf2f(gv.x >> 16);
            const float g2 = bf2f(gv.y & 0xffffu), g3 = bf2f(gv.y >> 16);
            const float w0 = lw[rb + k][0], w1 = lw[rb + k][1];
            const float w2 = lw[rb + k][2], w3 = lw[rb + k][3];
            ah0.x += g0 * w0; ah0.y += g1 * w0; ah0.z += g2 * w0; ah0.w += g3 * w0;
            ah1.x += g0 * w1; ah1.y += g1 * w1; ah1.z += g2 * w1; ah1.w += g3 * w1;
            ah2.x += g0 * w2; ah2.y += g1 * w2; ah2.z += g2 * w2; ah2.w += g3 * w2;
            ah3.x += g0 * w3; ah3.y += g1 * w3; ah3.z += g2 * w3; ah3.w += g3 * w3;
        }

        __syncthreads();   // previous round's shrink reads of a_s are done
        // a_s[slot][plane][c][h], plane stride PSTR=68: c = q*4 + j, h contig
        {
            const int q = l96 & 3, plane = l96 >> 2;
            float* ap = a_s + slot * ANS + plane * PSTR + q * 16;
            *(float4*)(ap + 0)  = make_float4(ah0.x, ah1.x, ah2.x, ah3.x);
            *(float4*)(ap + 4)  = make_float4(ah0.y, ah1.y, ah2.y, ah3.y);
            *(float4*)(ap + 8)  = make_float4(ah0.z, ah1.z, ah2.z, ah3.z);
            *(float4*)(ap + 12) = make_float4(ah0.w, ah1.w, ah2.w, ah3.w);
        }
        __syncthreads();

        // ---- shrink: 4 nodes x 384 outputs = 1536 -> 4 per thread ----
        #pragma unroll
        for (int j = 0; j < 4; ++j) {
            const int oid = tid + 384 * j;
            const int c   = oid & 15;
            const int r   = oid >> 4;          // 0..95
            const int o   = r % O_OUT;
            const int rr  = r / O_OUT;         // 0..7
            const int b   = rr & 1;
            const int ns  = rr >> 1;           // node slot
            const float* abase = a_s + ns * ANS + b * (T_IN * PSTR) + c * 4;
            const float* wbase = W_s + o * JJ;
            float y = b_s[o];
            #pragma unroll
            for (int t = 0; t < T_IN; ++t) {
                const float4 av = *(const float4*)(abase + t * PSTR);
                const float4 wv = *(const float4*)(wbase + t * 4);
                y += av.x * wv.x + av.y * wv.y + av.z * wv.z + av.w * wv.w;
            }
            y = (y > 0.0f) ? kScale * y : kScale * kAlpha * expm1f(y);
            const int n = n0 + g * 4 + ns;
            out[((b * T_OUT_ + T_IN + o) * NN + n) * CC + c] = y;
        }
    }
}

extern "C" void kernel_launch(void* const* d_in, const int* in_sizes, int n_in,
                              void* d_out, int out_size, void* d_ws, size_t ws_size,
                              hipStream_t stream) {
    const float* x     = (const float*)d_in[0];
    const int*   nodes = (const int*)  d_in[1];
    const float* dists = (const float*)d_in[2];
    const float* Wm    = (const float*)d_in[3];
    const float* bias  = (const float*)d_in[4];
    float* out = (float*)d_out;

    // ws layout: [0,4)=sigma (int bits) | 1024: xt (NN x 24 x 16 bf16, 7.68 MB)
    char* ws = (char*)d_ws;
    int*            sigma_bits = (int*)ws;
    unsigned short* xt         = (unsigned short*)(ws + 1024);

    const int ndists = in_sizes[2];  // N*K = 170000
    setup_kernel<<<TBLK + SBLK, 256, 0, stream>>>(x, dists, ndists, out, xt,
                                                  sigma_bits);
    fused_kernel<<<GBLK, 384, 0, stream>>>(xt, nodes, dists, sigma_bits,
                                           Wm, bias, out);
}